// Round 8
// baseline (555.208 us; speedup 1.0000x reference)
//
#include <hip/hip_runtime.h>
#include <math.h>

// Problem constants (fixed by setup_inputs)
constexpr int Bc  = 32;     // batch
constexpr int Dc  = 256;    // word feature dim
constexpr int Tc  = 32;     // seq len
constexpr int DHc = 128;    // image feature dim
constexpr int Nc  = 16384;  // H*W = 128*128

typedef _Float16 v8hf __attribute__((ext_vector_type(8)));
typedef _Float16 v2hf __attribute__((ext_vector_type(2)));
typedef float    v4f  __attribute__((ext_vector_type(4)));

// ---------------------------------------------------------------------------
// Stage 1: V = W·wf_b + bias, emitted directly as split-f16 buffers:
//   vth [b][t][k] (f16 hi)   vtl [b][t][k] (f16 lo)   vph [b][k][t] (f16 hi)
// grid: 32 b × 8 k-blocks of 16 = 256 blocks, 256 threads.
// Epilogue routes outputs through LDS transpose so ALL global writes are
// coalesced uint4 (the previous 2B/512B-stride stores had ~32x write
// amplification).
// ---------------------------------------------------------------------------
__global__ __launch_bounds__(256) void values_kernel(
    const float* __restrict__ wf, const float* __restrict__ Wm,
    const float* __restrict__ bias,
    _Float16* __restrict__ vth, _Float16* __restrict__ vtl,
    _Float16* __restrict__ vph)
{
    __shared__ float wfs[Dc * Tc];        // 32 KB  [d][t]  (reused by epilogue)
    __shared__ float Ws[16 * 260];        // 16.6 KB, padded rows

    const int tid = threadIdx.x;
    const int b   = blockIdx.x >> 3;
    const int k0  = (blockIdx.x & 7) * 16;

    {   // stage wf[b]: 8192 floats, coalesced float4
        const float4* src = (const float4*)(wf + (size_t)b * Dc * Tc);
        float4* dst = (float4*)wfs;
        #pragma unroll
        for (int i = 0; i < 8; ++i) dst[tid + 256 * i] = src[tid + 256 * i];
    }
    {   // stage W rows k0..k0+15: 4096 floats
        #pragma unroll
        for (int i = 0; i < 4; ++i) {
            int f = tid + 256 * i;            // float4 index
            int row = f >> 6, d4 = f & 63;
            *(float4*)&Ws[row * 260 + 4 * d4] =
                *(const float4*)&Wm[(size_t)(k0 + row) * Dc + 4 * d4];
        }
    }
    __syncthreads();

    const int kl  = tid >> 4;          // 0..15
    const int tt0 = (tid & 15) * 2;    // even t
    const int k   = k0 + kl;

    float acc0 = bias[k], acc1 = acc0;
    #pragma unroll
    for (int d4 = 0; d4 < 64; ++d4) {
        const float4 w4 = *(const float4*)&Ws[kl * 260 + 4 * d4];
        #pragma unroll
        for (int j = 0; j < 4; ++j) {
            const float2 f2 = *(const float2*)&wfs[(4 * d4 + j) * Tc + tt0];
            const float wv = (j == 0) ? w4.x : (j == 1) ? w4.y : (j == 2) ? w4.z : w4.w;
            acc0 = fmaf(wv, f2.x, acc0);
            acc1 = fmaf(wv, f2.y, acc1);
        }
    }

    _Float16 vh0 = (_Float16)acc0, vh1 = (_Float16)acc1;
    _Float16 vl0 = (_Float16)(acc0 - (float)vh0);
    _Float16 vl1 = (_Float16)(acc1 - (float)vh1);

    // ---- epilogue: LDS transpose staging, then coalesced uint4 writes ----
    __syncthreads();                         // done reading wfs
    _Float16* sh_h = (_Float16*)wfs;         // [16][32]  k-major (for vph)
    _Float16* th_h = sh_h + 16 * 32;         // [32][24]  t-major, padded (vth)
    _Float16* th_l = th_h + 32 * 24;         // [32][24]  t-major, padded (vtl)

    sh_h[kl * 32 + tt0]     = vh0;
    sh_h[kl * 32 + tt0 + 1] = vh1;
    th_h[tt0 * 24 + kl]       = vh0;
    th_h[(tt0 + 1) * 24 + kl] = vh1;
    th_l[tt0 * 24 + kl]       = vl0;
    th_l[(tt0 + 1) * 24 + kl] = vl1;
    __syncthreads();

    if (tid < 64) {          // vph [b][k0+row][t]: 16 rows x 64B, full segments
        int row = tid >> 2, ch = (tid & 3) * 8;
        *(uint4*)&vph[((size_t)b * DHc + k0 + row) * Tc + ch] =
            *(uint4*)&sh_h[row * 32 + ch];
    } else if (tid < 128) {  // vth [b][t][k0..k0+15]: 32 rows x 32B chunks
        int i = tid - 64; int t = i >> 1, hf = (i & 1) * 8;
        *(uint4*)&vth[((size_t)b * Tc + t) * DHc + k0 + hf] =
            *(uint4*)&th_h[t * 24 + hf];
    } else if (tid < 192) {  // vtl likewise
        int i = tid - 128; int t = i >> 1, hf = (i & 1) * 8;
        *(uint4*)&vtl[((size_t)b * Tc + t) * DHc + k0 + hf] =
            *(uint4*)&th_l[t * 24 + hf];
    }
}

__device__ __forceinline__ _Float16 pick_half(int u, int sel) {
    unsigned short s = (unsigned short)(sel ? (u >> 16) : u);
    return __builtin_bit_cast(_Float16, s);
}

__device__ __forceinline__ void nt_store4(float* p, float a, float b2, float c, float d) {
    v4f v; v[0] = a; v[1] = b2; v[2] = c; v[3] = d;
    __builtin_nontemporal_store(v, (v4f*)p);
}

// ---------------------------------------------------------------------------
// Stage 2 (MFMA): per 128-pixel strip of one batch (grid 4096, 2 iters/block).
//  staging = pure uint4 copies of pre-split V
//  Sᵀ = Vᵀ·Q (f16 hi/lo 3-term split), in-register masked softmax,
//  P relayout via shuffles, Oᵀ = Pᵀ·Vhᵀ with NONTEMPORAL dwordx4 stores
//  (outputs are write-once; keep them out of L2/L3 so img stays cached).
//  s_setprio(1) around MFMA clusters (waves are barrier-free post-staging —
//  the independent-phase regime where setprio measured positive on attn).
// ---------------------------------------------------------------------------
__global__ __launch_bounds__(256) void attn_kernel(
    const float* __restrict__ img,
    const _Float16* __restrict__ vth, const _Float16* __restrict__ vtl,
    const _Float16* __restrict__ vph,
    const int* __restrict__ mask, float* __restrict__ attn,
    float* __restrict__ coeff)
{
    constexpr int VT_LD = 136;  // k-stride (halves); 272B rows → ≤2-way banks
    constexpr int VP_LD = 40;   // t-stride (halves); 80B rows  → ≤2-way banks
    __shared__ __align__(16) _Float16 VTh[Tc * VT_LD];
    __shared__ __align__(16) _Float16 VTl[Tc * VT_LD];
    __shared__ __align__(16) _Float16 VPh[DHc * VP_LD];
    __shared__ float mneg[Tc];              // total ~27.8 KB

    const int tid   = threadIdx.x;
    const int b     = blockIdx.x >> 7;      // 128 strips per batch
    const int strip = blockIdx.x & 127;

    {   // staging: pure copies (512 chunks of 16B per buffer)
        const uint4* sth = (const uint4*)(vth + (size_t)b * Tc * DHc);
        const uint4* stl = (const uint4*)(vtl + (size_t)b * Tc * DHc);
        const uint4* sph = (const uint4*)(vph + (size_t)b * DHc * Tc);
        #pragma unroll
        for (int i = 0; i < 2; ++i) {
            int cid = tid + 256 * i;
            int t = cid >> 4, cc = cid & 15;        // 16 chunks per 128-half row
            *(uint4*)&VTh[t * VT_LD + 8 * cc] = sth[cid];
            *(uint4*)&VTl[t * VT_LD + 8 * cc] = stl[cid];
            int kk = cid >> 2, c4 = cid & 3;        // 4 chunks per 32-half row
            *(uint4*)&VPh[kk * VP_LD + 8 * c4] = sph[cid];
        }
        if (tid < Tc) mneg[tid] = mask[b * Tc + tid] ? -INFINITY : 0.0f;
    }
    __syncthreads();

    const int lane = tid & 63;
    const int wave = tid >> 6;
    const int c    = lane & 15;   // pixel column within 16-px tile
    const int g    = lane >> 4;   // lane group

    float madd[2][4];
    #pragma unroll
    for (int tt = 0; tt < 2; ++tt)
        #pragma unroll
        for (int r = 0; r < 4; ++r)
            madd[tt][r] = mneg[16 * tt + 4 * g + r];

    const float* qbase = img  + ((size_t)b * DHc + 8 * g) * Nc + c;
    float*       abase = attn + ((size_t)b * DHc + c) * Nc + 4 * g;  // Oᵀ store base
    float*       cbase = coeff + (size_t)b * Nc * Tc;

    const int ls_lo = c + 32 * (g & 1);
    const int sel   = g >> 1;

    #pragma unroll
    for (int it = 0; it < 2; ++it) {
        const int n0 = strip * 128 + (it * 4 + wave) * 16;

        // ---- load Q columns (lane = pixel c, k = ks*32+8g+j), split hi/lo ----
        const float* qp = qbase + n0;
        v8hf Qh[4], Ql[4];
        #pragma unroll
        for (int ks = 0; ks < 4; ++ks)
            #pragma unroll
            for (int j = 0; j < 8; ++j) {
                float qv = qp[(size_t)(ks * 32 + j) * Nc];
                _Float16 h = (_Float16)qv;
                Qh[ks][j] = h;
                Ql[ks][j] = (_Float16)(qv - (float)h);
            }

        // ---- Sᵀ = Vᵀ·Q : 2 t-tiles × 4 k-steps × 3 split terms ----
        v4f Sh[2], Sl[2];
        #pragma unroll
        for (int tt = 0; tt < 2; ++tt) {
            Sh[tt] = (v4f){0.f, 0.f, 0.f, 0.f};
            Sl[tt] = (v4f){0.f, 0.f, 0.f, 0.f};
        }
        __builtin_amdgcn_s_setprio(1);
        #pragma unroll
        for (int tt = 0; tt < 2; ++tt) {
            const int rowbase = (16 * tt + c) * VT_LD + 8 * g;
            #pragma unroll
            for (int ks = 0; ks < 4; ++ks) {
                v8hf va = *(const v8hf*)&VTh[rowbase + ks * 32];
                v8hf vl = *(const v8hf*)&VTl[rowbase + ks * 32];
                Sh[tt] = __builtin_amdgcn_mfma_f32_16x16x32_f16(va, Qh[ks], Sh[tt], 0, 0, 0);
                Sl[tt] = __builtin_amdgcn_mfma_f32_16x16x32_f16(va, Ql[ks], Sl[tt], 0, 0, 0);
                Sl[tt] = __builtin_amdgcn_mfma_f32_16x16x32_f16(vl, Qh[ks], Sl[tt], 0, 0, 0);
            }
        }
        __builtin_amdgcn_s_setprio(0);

        // ---- masked softmax over t ----
        float p0[4], p1[4];
        float m = -INFINITY;
        #pragma unroll
        for (int r = 0; r < 4; ++r) {
            p0[r] = Sh[0][r] + Sl[0][r] + madd[0][r];
            p1[r] = Sh[1][r] + Sl[1][r] + madd[1][r];
            m = fmaxf(m, fmaxf(p0[r], p1[r]));
        }
        m = fmaxf(m, __shfl_xor(m, 16));
        m = fmaxf(m, __shfl_xor(m, 32));
        float sum = 0.0f;
        #pragma unroll
        for (int r = 0; r < 4; ++r) {
            p0[r] = __expf(p0[r] - m); sum += p0[r];
            p1[r] = __expf(p1[r] - m); sum += p1[r];
        }
        sum += __shfl_xor(sum, 16);
        sum += __shfl_xor(sum, 32);
        const float inv = 1.0f / sum;
        #pragma unroll
        for (int r = 0; r < 4; ++r) { p0[r] *= inv; p1[r] *= inv; }

        // ---- coefficients [B,N,T]: nontemporal (write-once stream) ----
        float* cp = cbase + (size_t)(n0 + c) * Tc + 4 * g;
        nt_store4(cp,      p0[0], p0[1], p0[2], p0[3]);
        nt_store4(cp + 16, p1[0], p1[1], p1[2], p1[3]);

        // ---- relayout P: lane (c,g) gets t = 8g+j for pixel c ----
        v8hf Pb;
        #pragma unroll
        for (int r = 0; r < 4; ++r) {
            v2hf h2; h2[0] = (_Float16)p0[r]; h2[1] = (_Float16)p1[r];
            int u   = __builtin_bit_cast(int, h2);
            int ulo = __shfl(u, ls_lo);
            int uhi = __shfl(u, ls_lo + 16);
            Pb[r]     = pick_half(ulo, sel);
            Pb[4 + r] = pick_half(uhi, sel);
        }

        // ---- Oᵀ = Pᵀ·Vhᵀ : C/D row = pixel 4g+r, col = k=16mt+c → nt dwordx4 ----
        __builtin_amdgcn_s_setprio(1);
        #pragma unroll
        for (int mt = 0; mt < 8; ++mt) {
            v8hf vb2 = *(const v8hf*)&VPh[(16 * mt + c) * VP_LD + 8 * g];
            v4f o = (v4f){0.f, 0.f, 0.f, 0.f};
            o = __builtin_amdgcn_mfma_f32_16x16x32_f16(Pb, vb2, o, 0, 0, 0);
            float* ap = abase + (size_t)(16 * mt) * Nc + n0;
            nt_store4(ap, o[0], o[1], o[2], o[3]);
        }
        __builtin_amdgcn_s_setprio(0);
    }
}

extern "C" void kernel_launch(void* const* d_in, const int* in_sizes, int n_in,
                              void* d_out, int out_size, void* d_ws, size_t ws_size,
                              hipStream_t stream)
{
    const float* wf   = (const float*)d_in[0];  // [B,D,T]
    const float* img  = (const float*)d_in[1];  // [B,Dh,H,W]
    const int*   msk  = (const int*)d_in[2];    // [B,T]
    const float* Wm   = (const float*)d_in[3];  // [Dh,D]
    const float* bias = (const float*)d_in[4];  // [Dh]

    float* attn  = (float*)d_out;                        // [B,Dh,N]
    float* coeff = attn + (size_t)Bc * DHc * Nc;         // [B,N,T]

    // workspace: three split-f16 buffers of B*Dh*T halves each (256 KB each)
    _Float16* vth = (_Float16*)d_ws;
    _Float16* vtl = vth + (size_t)Bc * DHc * Tc;
    _Float16* vph = vtl + (size_t)Bc * DHc * Tc;

    values_kernel<<<256, 256, 0, stream>>>(wf, Wm, bias, vth, vtl, vph);
    attn_kernel<<<Bc * 128, 256, 0, stream>>>(img, vth, vtl, vph, msk, attn, coeff);
}

// Round 9
// 534.574 us; speedup vs baseline: 1.0386x; 1.0386x over previous
//
#include <hip/hip_runtime.h>
#include <math.h>

// Problem constants (fixed by setup_inputs)
constexpr int Bc  = 32;     // batch
constexpr int Dc  = 256;    // word feature dim
constexpr int Tc  = 32;     // seq len
constexpr int DHc = 128;    // image feature dim
constexpr int Nc  = 16384;  // H*W = 128*128

typedef _Float16 v8hf __attribute__((ext_vector_type(8)));
typedef _Float16 v2hf __attribute__((ext_vector_type(2)));
typedef float    v4f  __attribute__((ext_vector_type(4)));

// ---------------------------------------------------------------------------
// Stage 1: V = W·wf_b + bias, emitted directly as split-f16 buffers:
//   vth [b][t][k] (f16 hi)   vtl [b][t][k] (f16 lo)   vph [b][k][t] (f16 hi)
// grid: 32 b × 8 k-blocks of 16 = 256 blocks, 256 threads.
// Epilogue routes outputs through LDS transpose so ALL global writes are
// coalesced uint4 (2B/512B-stride stores had ~32x write amplification).
// ---------------------------------------------------------------------------
__global__ __launch_bounds__(256) void values_kernel(
    const float* __restrict__ wf, const float* __restrict__ Wm,
    const float* __restrict__ bias,
    _Float16* __restrict__ vth, _Float16* __restrict__ vtl,
    _Float16* __restrict__ vph)
{
    __shared__ float wfs[Dc * Tc];        // 32 KB  [d][t]  (reused by epilogue)
    __shared__ float Ws[16 * 260];        // 16.6 KB, padded rows

    const int tid = threadIdx.x;
    const int b   = blockIdx.x >> 3;
    const int k0  = (blockIdx.x & 7) * 16;

    {   // stage wf[b]: 8192 floats, coalesced float4
        const float4* src = (const float4*)(wf + (size_t)b * Dc * Tc);
        float4* dst = (float4*)wfs;
        #pragma unroll
        for (int i = 0; i < 8; ++i) dst[tid + 256 * i] = src[tid + 256 * i];
    }
    {   // stage W rows k0..k0+15: 4096 floats
        #pragma unroll
        for (int i = 0; i < 4; ++i) {
            int f = tid + 256 * i;            // float4 index
            int row = f >> 6, d4 = f & 63;
            *(float4*)&Ws[row * 260 + 4 * d4] =
                *(const float4*)&Wm[(size_t)(k0 + row) * Dc + 4 * d4];
        }
    }
    __syncthreads();

    const int kl  = tid >> 4;          // 0..15
    const int tt0 = (tid & 15) * 2;    // even t
    const int k   = k0 + kl;

    float acc0 = bias[k], acc1 = acc0;
    #pragma unroll
    for (int d4 = 0; d4 < 64; ++d4) {
        const float4 w4 = *(const float4*)&Ws[kl * 260 + 4 * d4];
        #pragma unroll
        for (int j = 0; j < 4; ++j) {
            const float2 f2 = *(const float2*)&wfs[(4 * d4 + j) * Tc + tt0];
            const float wv = (j == 0) ? w4.x : (j == 1) ? w4.y : (j == 2) ? w4.z : w4.w;
            acc0 = fmaf(wv, f2.x, acc0);
            acc1 = fmaf(wv, f2.y, acc1);
        }
    }

    _Float16 vh0 = (_Float16)acc0, vh1 = (_Float16)acc1;
    _Float16 vl0 = (_Float16)(acc0 - (float)vh0);
    _Float16 vl1 = (_Float16)(acc1 - (float)vh1);

    // ---- epilogue: LDS transpose staging, then coalesced uint4 writes ----
    __syncthreads();                         // done reading wfs
    _Float16* sh_h = (_Float16*)wfs;         // [16][32]  k-major (for vph)
    _Float16* th_h = sh_h + 16 * 32;         // [32][24]  t-major, padded (vth)
    _Float16* th_l = th_h + 32 * 24;         // [32][24]  t-major, padded (vtl)

    sh_h[kl * 32 + tt0]     = vh0;
    sh_h[kl * 32 + tt0 + 1] = vh1;
    th_h[tt0 * 24 + kl]       = vh0;
    th_h[(tt0 + 1) * 24 + kl] = vh1;
    th_l[tt0 * 24 + kl]       = vl0;
    th_l[(tt0 + 1) * 24 + kl] = vl1;
    __syncthreads();

    if (tid < 64) {          // vph [b][k0+row][t]: 16 rows x 64B, full segments
        int row = tid >> 2, ch = (tid & 3) * 8;
        *(uint4*)&vph[((size_t)b * DHc + k0 + row) * Tc + ch] =
            *(uint4*)&sh_h[row * 32 + ch];
    } else if (tid < 128) {  // vth [b][t][k0..k0+15]: 32 rows x 32B chunks
        int i = tid - 64; int t = i >> 1, hf = (i & 1) * 8;
        *(uint4*)&vth[((size_t)b * Tc + t) * DHc + k0 + hf] =
            *(uint4*)&th_h[t * 24 + hf];
    } else if (tid < 192) {  // vtl likewise
        int i = tid - 128; int t = i >> 1, hf = (i & 1) * 8;
        *(uint4*)&vtl[((size_t)b * Tc + t) * DHc + k0 + hf] =
            *(uint4*)&th_l[t * 24 + hf];
    }
}

__device__ __forceinline__ _Float16 pick_half(int u, int sel) {
    unsigned short s = (unsigned short)(sel ? (u >> 16) : u);
    return __builtin_bit_cast(_Float16, s);
}

// ---------------------------------------------------------------------------
// Stage 2 (MFMA): per 256-pixel strip of one batch (grid 2048 = r4 config,
// the best-measured attn configuration: 533 µs total).
//  staging = pure uint4 copies of pre-split V
//  Sᵀ = Vᵀ·Q (f16 hi/lo 3-term split), in-register masked softmax,
//  P relayout via shuffles, Oᵀ = Pᵀ·Vhᵀ with plain dwordx4 stores.
//  NO nontemporal (r8: +48MB write amplification), NO setprio (bundled in
//  r8's regression), NO manual prefetch (r5: neutral).
// ---------------------------------------------------------------------------
__global__ __launch_bounds__(256) void attn_kernel(
    const float* __restrict__ img,
    const _Float16* __restrict__ vth, const _Float16* __restrict__ vtl,
    const _Float16* __restrict__ vph,
    const int* __restrict__ mask, float* __restrict__ attn,
    float* __restrict__ coeff)
{
    constexpr int VT_LD = 136;  // k-stride (halves); 272B rows → ≤2-way banks
    constexpr int VP_LD = 40;   // t-stride (halves); 80B rows  → ≤2-way banks
    __shared__ __align__(16) _Float16 VTh[Tc * VT_LD];
    __shared__ __align__(16) _Float16 VTl[Tc * VT_LD];
    __shared__ __align__(16) _Float16 VPh[DHc * VP_LD];
    __shared__ float mneg[Tc];              // total ~27.8 KB

    const int tid   = threadIdx.x;
    const int b     = blockIdx.x >> 6;      // 64 strips per batch
    const int strip = blockIdx.x & 63;

    {   // staging: pure copies (512 chunks of 16B per buffer)
        const uint4* sth = (const uint4*)(vth + (size_t)b * Tc * DHc);
        const uint4* stl = (const uint4*)(vtl + (size_t)b * Tc * DHc);
        const uint4* sph = (const uint4*)(vph + (size_t)b * DHc * Tc);
        #pragma unroll
        for (int i = 0; i < 2; ++i) {
            int cid = tid + 256 * i;
            int t = cid >> 4, cc = cid & 15;        // 16 chunks per 128-half row
            *(uint4*)&VTh[t * VT_LD + 8 * cc] = sth[cid];
            *(uint4*)&VTl[t * VT_LD + 8 * cc] = stl[cid];
            int kk = cid >> 2, c4 = cid & 3;        // 4 chunks per 32-half row
            *(uint4*)&VPh[kk * VP_LD + 8 * c4] = sph[cid];
        }
        if (tid < Tc) mneg[tid] = mask[b * Tc + tid] ? -INFINITY : 0.0f;
    }
    __syncthreads();

    const int lane = tid & 63;
    const int wave = tid >> 6;
    const int c    = lane & 15;   // pixel column within 16-px tile
    const int g    = lane >> 4;   // lane group

    float madd[2][4];
    #pragma unroll
    for (int tt = 0; tt < 2; ++tt)
        #pragma unroll
        for (int r = 0; r < 4; ++r)
            madd[tt][r] = mneg[16 * tt + 4 * g + r];

    const float* qbase = img  + ((size_t)b * DHc + 8 * g) * Nc + c;
    float*       abase = attn + ((size_t)b * DHc + c) * Nc + 4 * g;  // Oᵀ store base
    float*       cbase = coeff + (size_t)b * Nc * Tc;

    const int ls_lo = c + 32 * (g & 1);
    const int sel   = g >> 1;

    #pragma unroll 2
    for (int it = 0; it < 4; ++it) {
        const int n0 = strip * 256 + (it * 4 + wave) * 16;

        // ---- load Q columns (lane = pixel c, k = ks*32+8g+j), split hi/lo ----
        const float* qp = qbase + n0;
        v8hf Qh[4], Ql[4];
        #pragma unroll
        for (int ks = 0; ks < 4; ++ks)
            #pragma unroll
            for (int j = 0; j < 8; ++j) {
                float qv = qp[(size_t)(ks * 32 + j) * Nc];
                _Float16 h = (_Float16)qv;
                Qh[ks][j] = h;
                Ql[ks][j] = (_Float16)(qv - (float)h);
            }

        // ---- Sᵀ = Vᵀ·Q : 2 t-tiles × 4 k-steps × 3 split terms ----
        v4f Sh[2], Sl[2];
        #pragma unroll
        for (int tt = 0; tt < 2; ++tt) {
            Sh[tt] = (v4f){0.f, 0.f, 0.f, 0.f};
            Sl[tt] = (v4f){0.f, 0.f, 0.f, 0.f};
        }
        #pragma unroll
        for (int tt = 0; tt < 2; ++tt) {
            const int rowbase = (16 * tt + c) * VT_LD + 8 * g;
            #pragma unroll
            for (int ks = 0; ks < 4; ++ks) {
                v8hf va = *(const v8hf*)&VTh[rowbase + ks * 32];
                v8hf vl = *(const v8hf*)&VTl[rowbase + ks * 32];
                Sh[tt] = __builtin_amdgcn_mfma_f32_16x16x32_f16(va, Qh[ks], Sh[tt], 0, 0, 0);
                Sl[tt] = __builtin_amdgcn_mfma_f32_16x16x32_f16(va, Ql[ks], Sl[tt], 0, 0, 0);
                Sl[tt] = __builtin_amdgcn_mfma_f32_16x16x32_f16(vl, Qh[ks], Sl[tt], 0, 0, 0);
            }
        }

        // ---- masked softmax over t ----
        float p0[4], p1[4];
        float m = -INFINITY;
        #pragma unroll
        for (int r = 0; r < 4; ++r) {
            p0[r] = Sh[0][r] + Sl[0][r] + madd[0][r];
            p1[r] = Sh[1][r] + Sl[1][r] + madd[1][r];
            m = fmaxf(m, fmaxf(p0[r], p1[r]));
        }
        m = fmaxf(m, __shfl_xor(m, 16));
        m = fmaxf(m, __shfl_xor(m, 32));
        float sum = 0.0f;
        #pragma unroll
        for (int r = 0; r < 4; ++r) {
            p0[r] = __expf(p0[r] - m); sum += p0[r];
            p1[r] = __expf(p1[r] - m); sum += p1[r];
        }
        sum += __shfl_xor(sum, 16);
        sum += __shfl_xor(sum, 32);
        const float inv = 1.0f / sum;
        #pragma unroll
        for (int r = 0; r < 4; ++r) { p0[r] *= inv; p1[r] *= inv; }

        // ---- coefficients [B,N,T] ----
        float* cp = cbase + (size_t)(n0 + c) * Tc + 4 * g;
        *(float4*)cp        = make_float4(p0[0], p0[1], p0[2], p0[3]);
        *(float4*)(cp + 16) = make_float4(p1[0], p1[1], p1[2], p1[3]);

        // ---- relayout P: lane (c,g) gets t = 8g+j for pixel c ----
        v8hf Pb;
        #pragma unroll
        for (int r = 0; r < 4; ++r) {
            v2hf h2; h2[0] = (_Float16)p0[r]; h2[1] = (_Float16)p1[r];
            int u   = __builtin_bit_cast(int, h2);
            int ulo = __shfl(u, ls_lo);
            int uhi = __shfl(u, ls_lo + 16);
            Pb[r]     = pick_half(ulo, sel);
            Pb[4 + r] = pick_half(uhi, sel);
        }

        // ---- Oᵀ = Pᵀ·Vhᵀ : C/D row = pixel 4g+r, col = k=16mt+c → dwordx4 ----
        #pragma unroll
        for (int mt = 0; mt < 8; ++mt) {
            v8hf vb2 = *(const v8hf*)&VPh[(16 * mt + c) * VP_LD + 8 * g];
            v4f o = (v4f){0.f, 0.f, 0.f, 0.f};
            o = __builtin_amdgcn_mfma_f32_16x16x32_f16(Pb, vb2, o, 0, 0, 0);
            float* ap = abase + (size_t)(16 * mt) * Nc + n0;
            *(float4*)ap = make_float4(o[0], o[1], o[2], o[3]);
        }
    }
}

extern "C" void kernel_launch(void* const* d_in, const int* in_sizes, int n_in,
                              void* d_out, int out_size, void* d_ws, size_t ws_size,
                              hipStream_t stream)
{
    const float* wf   = (const float*)d_in[0];  // [B,D,T]
    const float* img  = (const float*)d_in[1];  // [B,Dh,H,W]
    const int*   msk  = (const int*)d_in[2];    // [B,T]
    const float* Wm   = (const float*)d_in[3];  // [Dh,D]
    const float* bias = (const float*)d_in[4];  // [Dh]

    float* attn  = (float*)d_out;                        // [B,Dh,N]
    float* coeff = attn + (size_t)Bc * DHc * Nc;         // [B,N,T]

    // workspace: three split-f16 buffers of B*Dh*T halves each (256 KB each)
    _Float16* vth = (_Float16*)d_ws;
    _Float16* vtl = vth + (size_t)Bc * DHc * Tc;
    _Float16* vph = vtl + (size_t)Bc * DHc * Tc;

    values_kernel<<<256, 256, 0, stream>>>(wf, Wm, bias, vth, vtl, vph);
    attn_kernel<<<Bc * 64, 256, 0, stream>>>(img, vth, vtl, vph, msk, attn, coeff);
}

// Round 10
// 521.551 us; speedup vs baseline: 1.0645x; 1.0250x over previous
//
#include <hip/hip_runtime.h>
#include <math.h>

// Problem constants (fixed by setup_inputs)
constexpr int Bc  = 32;     // batch
constexpr int Dc  = 256;    // word feature dim
constexpr int Tc  = 32;     // seq len
constexpr int DHc = 128;    // image feature dim
constexpr int Nc  = 16384;  // H*W = 128*128

typedef _Float16 v8hf __attribute__((ext_vector_type(8)));
typedef _Float16 v2hf __attribute__((ext_vector_type(2)));
typedef float    v4f  __attribute__((ext_vector_type(4)));

// ---------------------------------------------------------------------------
// Stage 1: V = W·wf_b + bias, emitted directly as split-f16 buffers:
//   vth [b][t][k] (f16 hi)   vtl [b][t][k] (f16 lo)   vph [b][k][t] (f16 hi)
// grid: 32 b × 8 k-blocks of 16 = 256 blocks, 256 threads.
// ---------------------------------------------------------------------------
__global__ __launch_bounds__(256) void values_kernel(
    const float* __restrict__ wf, const float* __restrict__ Wm,
    const float* __restrict__ bias,
    _Float16* __restrict__ vth, _Float16* __restrict__ vtl,
    _Float16* __restrict__ vph)
{
    __shared__ float wfs[Dc * Tc];        // 32 KB  [d][t]  (reused by epilogue)
    __shared__ float Ws[16 * 260];        // 16.6 KB, padded rows

    const int tid = threadIdx.x;
    const int b   = blockIdx.x >> 3;
    const int k0  = (blockIdx.x & 7) * 16;

    {   // stage wf[b]: 8192 floats, coalesced float4
        const float4* src = (const float4*)(wf + (size_t)b * Dc * Tc);
        float4* dst = (float4*)wfs;
        #pragma unroll
        for (int i = 0; i < 8; ++i) dst[tid + 256 * i] = src[tid + 256 * i];
    }
    {   // stage W rows k0..k0+15: 4096 floats
        #pragma unroll
        for (int i = 0; i < 4; ++i) {
            int f = tid + 256 * i;            // float4 index
            int row = f >> 6, d4 = f & 63;
            *(float4*)&Ws[row * 260 + 4 * d4] =
                *(const float4*)&Wm[(size_t)(k0 + row) * Dc + 4 * d4];
        }
    }
    __syncthreads();

    const int kl  = tid >> 4;          // 0..15
    const int tt0 = (tid & 15) * 2;    // even t
    const int k   = k0 + kl;

    float acc0 = bias[k], acc1 = acc0;
    #pragma unroll
    for (int d4 = 0; d4 < 64; ++d4) {
        const float4 w4 = *(const float4*)&Ws[kl * 260 + 4 * d4];
        #pragma unroll
        for (int j = 0; j < 4; ++j) {
            const float2 f2 = *(const float2*)&wfs[(4 * d4 + j) * Tc + tt0];
            const float wv = (j == 0) ? w4.x : (j == 1) ? w4.y : (j == 2) ? w4.z : w4.w;
            acc0 = fmaf(wv, f2.x, acc0);
            acc1 = fmaf(wv, f2.y, acc1);
        }
    }

    _Float16 vh0 = (_Float16)acc0, vh1 = (_Float16)acc1;
    _Float16 vl0 = (_Float16)(acc0 - (float)vh0);
    _Float16 vl1 = (_Float16)(acc1 - (float)vh1);

    // ---- epilogue: LDS transpose staging, then coalesced uint4 writes ----
    __syncthreads();                         // done reading wfs
    _Float16* sh_h = (_Float16*)wfs;         // [16][32]  k-major (for vph)
    _Float16* th_h = sh_h + 16 * 32;         // [32][24]  t-major, padded (vth)
    _Float16* th_l = th_h + 32 * 24;         // [32][24]  t-major, padded (vtl)

    sh_h[kl * 32 + tt0]     = vh0;
    sh_h[kl * 32 + tt0 + 1] = vh1;
    th_h[tt0 * 24 + kl]       = vh0;
    th_h[(tt0 + 1) * 24 + kl] = vh1;
    th_l[tt0 * 24 + kl]       = vl0;
    th_l[(tt0 + 1) * 24 + kl] = vl1;
    __syncthreads();

    if (tid < 64) {          // vph [b][k0+row][t]: 16 rows x 64B, full segments
        int row = tid >> 2, ch = (tid & 3) * 8;
        *(uint4*)&vph[((size_t)b * DHc + k0 + row) * Tc + ch] =
            *(uint4*)&sh_h[row * 32 + ch];
    } else if (tid < 128) {  // vth [b][t][k0..k0+15]: 32 rows x 32B chunks
        int i = tid - 64; int t = i >> 1, hf = (i & 1) * 8;
        *(uint4*)&vth[((size_t)b * Tc + t) * DHc + k0 + hf] =
            *(uint4*)&th_h[t * 24 + hf];
    } else if (tid < 192) {  // vtl likewise
        int i = tid - 128; int t = i >> 1, hf = (i & 1) * 8;
        *(uint4*)&vtl[((size_t)b * Tc + t) * DHc + k0 + hf] =
            *(uint4*)&th_l[t * 24 + hf];
    }
}

__device__ __forceinline__ _Float16 pick_half(int u, int sel) {
    unsigned short s = (unsigned short)(sel ? (u >> 16) : u);
    return __builtin_bit_cast(_Float16, s);
}

// ---------------------------------------------------------------------------
// Stage 2 (MFMA): per 256-pixel strip (grid 2048), TWO 16-px tiles per wave
// per iteration (A at n0, B at n0+16):
//   - two independent QK/softmax/PV chains → ILP x2 for the scheduler
//   - 64 Q loads in flight (MLP x2)
//   - each V LDS read (va/vl/vb2) feeds BOTH tiles → LDS traffic halved
//   - attn stores pair into 128B contiguous segments
// ---------------------------------------------------------------------------
__global__ __launch_bounds__(256) void attn_kernel(
    const float* __restrict__ img,
    const _Float16* __restrict__ vth, const _Float16* __restrict__ vtl,
    const _Float16* __restrict__ vph,
    const int* __restrict__ mask, float* __restrict__ attn,
    float* __restrict__ coeff)
{
    constexpr int VT_LD = 136;  // k-stride (halves); 272B rows → ≤2-way banks
    constexpr int VP_LD = 40;   // t-stride (halves); 80B rows  → ≤2-way banks
    __shared__ __align__(16) _Float16 VTh[Tc * VT_LD];
    __shared__ __align__(16) _Float16 VTl[Tc * VT_LD];
    __shared__ __align__(16) _Float16 VPh[DHc * VP_LD];
    __shared__ float mneg[Tc];              // total ~27.8 KB

    const int tid   = threadIdx.x;
    const int b     = blockIdx.x >> 6;      // 64 strips per batch
    const int strip = blockIdx.x & 63;

    {   // staging: pure copies (512 chunks of 16B per buffer)
        const uint4* sth = (const uint4*)(vth + (size_t)b * Tc * DHc);
        const uint4* stl = (const uint4*)(vtl + (size_t)b * Tc * DHc);
        const uint4* sph = (const uint4*)(vph + (size_t)b * DHc * Tc);
        #pragma unroll
        for (int i = 0; i < 2; ++i) {
            int cid = tid + 256 * i;
            int t = cid >> 4, cc = cid & 15;        // 16 chunks per 128-half row
            *(uint4*)&VTh[t * VT_LD + 8 * cc] = sth[cid];
            *(uint4*)&VTl[t * VT_LD + 8 * cc] = stl[cid];
            int kk = cid >> 2, c4 = cid & 3;        // 4 chunks per 32-half row
            *(uint4*)&VPh[kk * VP_LD + 8 * c4] = sph[cid];
        }
        if (tid < Tc) mneg[tid] = mask[b * Tc + tid] ? -INFINITY : 0.0f;
    }
    __syncthreads();

    const int lane = tid & 63;
    const int wave = tid >> 6;
    const int c    = lane & 15;   // pixel column within 16-px tile
    const int g    = lane >> 4;   // lane group

    float madd[2][4];
    #pragma unroll
    for (int tt = 0; tt < 2; ++tt)
        #pragma unroll
        for (int r = 0; r < 4; ++r)
            madd[tt][r] = mneg[16 * tt + 4 * g + r];

    const float* qbase = img  + ((size_t)b * DHc + 8 * g) * Nc + c;
    float*       abase = attn + ((size_t)b * DHc + c) * Nc + 4 * g;  // Oᵀ store base
    float*       cbase = coeff + (size_t)b * Nc * Tc;

    const int ls_lo = c + 32 * (g & 1);
    const int sel   = g >> 1;

    #pragma unroll
    for (int it = 0; it < 2; ++it) {
        // wave covers 32 px: tile A at n0, tile B at n0+16
        const int n0 = strip * 256 + it * 128 + wave * 32;

        // ---- load Q for both tiles (lane = pixel c / c+16), split hi/lo ----
        const float* qp = qbase + n0;
        v8hf QhA[4], QlA[4], QhB[4], QlB[4];
        #pragma unroll
        for (int ks = 0; ks < 4; ++ks)
            #pragma unroll
            for (int j = 0; j < 8; ++j) {
                const size_t off = (size_t)(ks * 32 + j) * Nc;
                float qa = qp[off];
                float qb = qp[off + 16];
                _Float16 ha = (_Float16)qa;
                _Float16 hb = (_Float16)qb;
                QhA[ks][j] = ha; QlA[ks][j] = (_Float16)(qa - (float)ha);
                QhB[ks][j] = hb; QlB[ks][j] = (_Float16)(qb - (float)hb);
            }

        // ---- Sᵀ = Vᵀ·Q for both tiles: shared V reads, 6 MFMA per (tt,ks) ----
        v4f ShA[2], SlA[2], ShB[2], SlB[2];
        #pragma unroll
        for (int tt = 0; tt < 2; ++tt) {
            ShA[tt] = (v4f){0.f, 0.f, 0.f, 0.f};
            SlA[tt] = (v4f){0.f, 0.f, 0.f, 0.f};
            ShB[tt] = (v4f){0.f, 0.f, 0.f, 0.f};
            SlB[tt] = (v4f){0.f, 0.f, 0.f, 0.f};
        }
        #pragma unroll
        for (int tt = 0; tt < 2; ++tt) {
            const int rowbase = (16 * tt + c) * VT_LD + 8 * g;
            #pragma unroll
            for (int ks = 0; ks < 4; ++ks) {
                v8hf va = *(const v8hf*)&VTh[rowbase + ks * 32];
                v8hf vl = *(const v8hf*)&VTl[rowbase + ks * 32];
                ShA[tt] = __builtin_amdgcn_mfma_f32_16x16x32_f16(va, QhA[ks], ShA[tt], 0, 0, 0);
                ShB[tt] = __builtin_amdgcn_mfma_f32_16x16x32_f16(va, QhB[ks], ShB[tt], 0, 0, 0);
                SlA[tt] = __builtin_amdgcn_mfma_f32_16x16x32_f16(va, QlA[ks], SlA[tt], 0, 0, 0);
                SlB[tt] = __builtin_amdgcn_mfma_f32_16x16x32_f16(va, QlB[ks], SlB[tt], 0, 0, 0);
                SlA[tt] = __builtin_amdgcn_mfma_f32_16x16x32_f16(vl, QhA[ks], SlA[tt], 0, 0, 0);
                SlB[tt] = __builtin_amdgcn_mfma_f32_16x16x32_f16(vl, QhB[ks], SlB[tt], 0, 0, 0);
            }
        }

        // ---- masked softmax over t, both tiles (independent chains) ----
        float p0A[4], p1A[4], p0B[4], p1B[4];
        float mA = -INFINITY, mB = -INFINITY;
        #pragma unroll
        for (int r = 0; r < 4; ++r) {
            p0A[r] = ShA[0][r] + SlA[0][r] + madd[0][r];
            p1A[r] = ShA[1][r] + SlA[1][r] + madd[1][r];
            p0B[r] = ShB[0][r] + SlB[0][r] + madd[0][r];
            p1B[r] = ShB[1][r] + SlB[1][r] + madd[1][r];
            mA = fmaxf(mA, fmaxf(p0A[r], p1A[r]));
            mB = fmaxf(mB, fmaxf(p0B[r], p1B[r]));
        }
        mA = fmaxf(mA, __shfl_xor(mA, 16));
        mA = fmaxf(mA, __shfl_xor(mA, 32));
        mB = fmaxf(mB, __shfl_xor(mB, 16));
        mB = fmaxf(mB, __shfl_xor(mB, 32));
        float sumA = 0.0f, sumB = 0.0f;
        #pragma unroll
        for (int r = 0; r < 4; ++r) {
            p0A[r] = __expf(p0A[r] - mA); sumA += p0A[r];
            p1A[r] = __expf(p1A[r] - mA); sumA += p1A[r];
            p0B[r] = __expf(p0B[r] - mB); sumB += p0B[r];
            p1B[r] = __expf(p1B[r] - mB); sumB += p1B[r];
        }
        sumA += __shfl_xor(sumA, 16);
        sumA += __shfl_xor(sumA, 32);
        sumB += __shfl_xor(sumB, 16);
        sumB += __shfl_xor(sumB, 32);
        const float invA = 1.0f / sumA, invB = 1.0f / sumB;
        #pragma unroll
        for (int r = 0; r < 4; ++r) {
            p0A[r] *= invA; p1A[r] *= invA;
            p0B[r] *= invB; p1B[r] *= invB;
        }

        // ---- coefficients [B,N,T] for both tiles ----
        {
            float* cpA = cbase + (size_t)(n0 + c) * Tc + 4 * g;
            float* cpB = cbase + (size_t)(n0 + 16 + c) * Tc + 4 * g;
            *(float4*)cpA        = make_float4(p0A[0], p0A[1], p0A[2], p0A[3]);
            *(float4*)(cpA + 16) = make_float4(p1A[0], p1A[1], p1A[2], p1A[3]);
            *(float4*)cpB        = make_float4(p0B[0], p0B[1], p0B[2], p0B[3]);
            *(float4*)(cpB + 16) = make_float4(p1B[0], p1B[1], p1B[2], p1B[3]);
        }

        // ---- relayout P for both tiles ----
        v8hf PbA, PbB;
        #pragma unroll
        for (int r = 0; r < 4; ++r) {
            v2hf hA; hA[0] = (_Float16)p0A[r]; hA[1] = (_Float16)p1A[r];
            v2hf hB; hB[0] = (_Float16)p0B[r]; hB[1] = (_Float16)p1B[r];
            int uA = __builtin_bit_cast(int, hA);
            int uB = __builtin_bit_cast(int, hB);
            int uAlo = __shfl(uA, ls_lo);
            int uAhi = __shfl(uA, ls_lo + 16);
            int uBlo = __shfl(uB, ls_lo);
            int uBhi = __shfl(uB, ls_lo + 16);
            PbA[r]     = pick_half(uAlo, sel);
            PbA[4 + r] = pick_half(uAhi, sel);
            PbB[r]     = pick_half(uBlo, sel);
            PbB[4 + r] = pick_half(uBhi, sel);
        }

        // ---- Oᵀ = Pᵀ·Vhᵀ both tiles: shared vb2 read, paired 64B stores ----
        #pragma unroll
        for (int mt = 0; mt < 8; ++mt) {
            v8hf vb2 = *(const v8hf*)&VPh[(16 * mt + c) * VP_LD + 8 * g];
            v4f oA = (v4f){0.f, 0.f, 0.f, 0.f};
            v4f oB = (v4f){0.f, 0.f, 0.f, 0.f};
            oA = __builtin_amdgcn_mfma_f32_16x16x32_f16(PbA, vb2, oA, 0, 0, 0);
            oB = __builtin_amdgcn_mfma_f32_16x16x32_f16(PbB, vb2, oB, 0, 0, 0);
            float* ap = abase + (size_t)(16 * mt) * Nc + n0;
            *(float4*)ap        = make_float4(oA[0], oA[1], oA[2], oA[3]);
            *(float4*)(ap + 16) = make_float4(oB[0], oB[1], oB[2], oB[3]);
        }
    }
}

extern "C" void kernel_launch(void* const* d_in, const int* in_sizes, int n_in,
                              void* d_out, int out_size, void* d_ws, size_t ws_size,
                              hipStream_t stream)
{
    const float* wf   = (const float*)d_in[0];  // [B,D,T]
    const float* img  = (const float*)d_in[1];  // [B,Dh,H,W]
    const int*   msk  = (const int*)d_in[2];    // [B,T]
    const float* Wm   = (const float*)d_in[3];  // [Dh,D]
    const float* bias = (const float*)d_in[4];  // [Dh]

    float* attn  = (float*)d_out;                        // [B,Dh,N]
    float* coeff = attn + (size_t)Bc * DHc * Nc;         // [B,N,T]

    // workspace: three split-f16 buffers of B*Dh*T halves each (256 KB each)
    _Float16* vth = (_Float16*)d_ws;
    _Float16* vtl = vth + (size_t)Bc * DHc * Tc;
    _Float16* vph = vtl + (size_t)Bc * DHc * Tc;

    values_kernel<<<256, 256, 0, stream>>>(wf, Wm, bias, vth, vtl, vph);
    attn_kernel<<<Bc * 64, 256, 0, stream>>>(img, vth, vtl, vph, msk, attn, coeff);
}